// Round 1
// 7526.822 us; speedup vs baseline: 1.0276x; 1.0276x over previous
//
#include <hip/hip_runtime.h>

// SNN-MNIST forward + STDP, MI355X persistent cooperative kernel.
// Round 5: (1) all-to-all flag grid barrier (parallel arrival stores +
// self-poll, no RMW chains / no propagation hops); (2) flags[t] 256-way
// atomic OR replaced by per-block anyspk bits; (3) phase-2 tr/img staged
// into persistent LDS during the previous step's epilogue (chunk loop
// stages sppo only, vmcnt(2)); (4) 16-deep gather; (5) ballot win-reduce.

#define T_STEPS 200
#define BATCH   256
#define INQ     784
#define NOUT    400
#define NP      512
#define GRID    256
#define NTHR    256

// ws layout (float offsets)
#define OFF_WT    0            // Wt [785][512] (row 784 = zero pad for gather)
#define OFF_SYN   401920       // syn [256][512]         (block-private)
#define OFF_MEM   532992       // mem [256][512]         (block-private)
#define OFF_SPPO  664064       // interleaved (spk,post): [256][1024]  (sc1)
#define OFF_TRA   926208       // trA [256][784]         (sc1)
#define OFF_TRB   1126912      // trB [256][784]         (sc1)
#define OFF_WIN   1327616      // int win[256]           (block-private)
#define OFF_ANY   1327872      // u32 anyspk[2][256]     (sc1, ping-pong)
#define OFF_BARF  1328384      // u32 barf[256]: all-to-all barrier flags
#define WS_FLOATS 1332224

// ---- agent-coherent (sc1) access helpers ----
__device__ __forceinline__ float ld_coh(const float* p) {
  return __hip_atomic_load(p, __ATOMIC_RELAXED, __HIP_MEMORY_SCOPE_AGENT);
}
__device__ __forceinline__ float2 ld_coh2(const float* p) {
  union { unsigned long long u; float2 f; } c;
  c.u = __hip_atomic_load((const unsigned long long*)p, __ATOMIC_RELAXED,
                          __HIP_MEMORY_SCOPE_AGENT);
  return c.f;
}
__device__ __forceinline__ void st_coh(float* p, float v) {
  __hip_atomic_store(p, v, __ATOMIC_RELAXED, __HIP_MEMORY_SCOPE_AGENT);
}
__device__ __forceinline__ void st_coh2(float* p, float2 v) {
  union { unsigned long long u; float2 f; } c; c.f = v;
  __hip_atomic_store((unsigned long long*)p, c.u, __ATOMIC_RELAXED,
                     __HIP_MEMORY_SCOPE_AGENT);
}
__device__ __forceinline__ void st_cohu(unsigned* p, unsigned v) {
  __hip_atomic_store(p, v, __ATOMIC_RELAXED, __HIP_MEMORY_SCOPE_AGENT);
}
__device__ __forceinline__ unsigned long long ld_cohu64(const unsigned long long* p) {
  return __hip_atomic_load(p, __ATOMIC_RELAXED, __HIP_MEMORY_SCOPE_AGENT);
}

__device__ __forceinline__ void gl_lds16(const float* g, float* l) {       // cached
  __builtin_amdgcn_global_load_lds(
      (const __attribute__((address_space(1))) void*)g,
      (__attribute__((address_space(3))) void*)l, 16, 0, 0);
}
__device__ __forceinline__ void gl_lds16c(const float* g, float* l) {      // sc1
  __builtin_amdgcn_global_load_lds(
      (const __attribute__((address_space(1))) void*)g,
      (__attribute__((address_space(3))) void*)l, 16, 0, 0x10);
}

// All-to-all flag barrier, k = 1-based ordinal. Arrival: each block STORES
// its own flag (16 lines total, no RMW contention). Release: wave 0 of every
// block polls all 256 flags (2 x 8B loads/lane) -- one L3 round-trip after
// the last arrival, no propagation chain. __syncthreads() before arrival
// drains vmcnt, making prior write-through stores globally visible.
__device__ __forceinline__ void gbar(unsigned* barf, unsigned k, int blk) {
  __syncthreads();
  if (threadIdx.x == 0)
    st_cohu(barf + blk, k);
  if (threadIdx.x < 64) {
    const unsigned long long* p =
        (const unsigned long long*)barf + (threadIdx.x << 1);
    for (;;) {
      unsigned long long a = ld_cohu64(p);
      unsigned long long bq = ld_cohu64(p + 1);
      unsigned m0 = (unsigned)a, m1 = (unsigned)(a >> 32);
      unsigned m2 = (unsigned)bq, m3 = (unsigned)(bq >> 32);
      unsigned mn = m0 < m1 ? m0 : m1;
      unsigned mo = m2 < m3 ? m2 : m3;
      mn = mn < mo ? mn : mo;
      if (__all(mn >= k)) break;
      __builtin_amdgcn_s_sleep(1);
    }
  }
  __syncthreads();
}

__global__ void __launch_bounds__(NTHR) snn_kernel(
    const float* __restrict__ img,   // [200][256][784]
    const float* __restrict__ Win,   // [400][784]
    float* __restrict__ out,         // mem_rec | spk_rec | W_final
    float* ws)
{
  float* Wt    = ws + OFF_WT;
  float* syn   = ws + OFF_SYN;
  float* mem   = ws + OFF_MEM;
  float* sppo  = ws + OFF_SPPO;
  float* trA   = ws + OFF_TRA;
  float* trB   = ws + OFF_TRB;
  int*   win   = (int*)(ws + OFF_WIN);
  unsigned* anyspk = (unsigned*)(ws + OFF_ANY);
  unsigned* barf   = (unsigned*)(ws + OFF_BARF);

  float* mem_rec = out;
  float* spk_rec = out + (size_t)T_STEPS * BATCH * NOUT;
  float* Wout    = out + (size_t)2 * T_STEPS * BATCH * NOUT;

  const int tid = threadIdx.x;
  const int blk = blockIdx.x;
  unsigned bt = 0;                    // barrier ordinal

  __shared__ float stg_tr[16384];     // tr  [256][64]  (persistent per step)
  __shared__ float stg_im[16384];     // img [256][64]  (persistent per step)
  __shared__ float stg_sp[2][2048];   // sppo chunk dbuf [32][64]
  __shared__ int s_list[800];
  __shared__ int s_cnt, s_any;
  __shared__ int s_red[4];

  // phase-2 tile geometry (also used for prefetch)
  const int p2w = tid >> 6, p2l = tid & 63;
  const int bi = blk / 13, bn = blk % 13;
  const int ib0 = bi * 64, nb0 = bn * 32;
  int icol = ib0 + (p2l & 15) * 4;
  if (icol > INQ - 4) icol = INQ - 4;           // clamp (garbage, unused)
  const int scol = 2 * nb0 + (p2l & 15) * 4;

  // ---- init: Wt[i][n] = Win[n][i], written coherently ----
  for (int e = blk * NTHR + tid; e < NOUT * INQ; e += GRID * NTHR) {
    int n = e / INQ, i = e % INQ;
    st_coh(Wt + (size_t)i * NP + n, Win[e]);
  }
  // prefetch step-0 tr (zeros) + img into persistent LDS
  if (blk < 169) {
    #pragma unroll
    for (int q = 0; q < 16; ++q) {
      int br = q * 16 + p2w * 4 + (p2l >> 4);
      gl_lds16c(trA + (size_t)br * INQ + icol, &stg_tr[(q * 16 + p2w * 4) * 64]);
      gl_lds16 (img + (size_t)br * INQ + icol, &stg_im[(q * 16 + p2w * 4) * 64]);
    }
  }
  ++bt; gbar(barf, bt, blk);

  for (int t = 0; t < T_STEPS; ++t) {
    float* trC = (t & 1) ? trB : trA;   // pre_traces[t]
    float* trN = (t & 1) ? trA : trB;   // pre_traces[t+1]

    // ================= phase 1: block b = batch row =================
    {
      const int b = blk;
      const float* imrow = img + ((size_t)t * BATCH + b) * INQ;
      float* trCrow = trC + (size_t)b * INQ;
      float* trNrow = trN + (size_t)b * INQ;
      if (tid >= 64) {
        // waves 1-3: trace recurrence tr_{t+1} = 0.9*tr_t + img_t
        for (int i = tid - 64; i < INQ; i += NTHR - 64)
          st_coh(trNrow + i, fmaf(0.9f, ld_coh(trCrow + i), imrow[i]));
      } else {
        // wave 0: issue global any-spike gather first (overlaps compaction)
        unsigned long long ax = 0ull, ay = 0ull;
        if (t > 0) {
          const unsigned long long* ap =
              (const unsigned long long*)(anyspk + ((t - 1) & 1) * 256) +
              (tid << 1);
          ax = ld_cohu64(ap);
          ay = ld_cohu64(ap + 1);
        }
        // ordered active-index compaction, padded to multiple of 16
        int base = 0;
        for (int c = 0; c < INQ; c += 64) {
          int i = c + tid;
          bool act = (i < INQ) && (imrow[i] != 0.0f);
          unsigned long long m = __ballot(act);
          if (act) s_list[base + (int)__popcll(m & ((1ull << tid) - 1ull))] = i;
          base += (int)__popcll(m);
        }
        int anyv = __any((ax | ay) != 0ull);
        if (tid == 0) {
          int cr = (base + 15) & ~15;
          for (int j = base; j < cr; ++j) s_list[j] = 784;  // zero pad row
          s_cnt = cr;
          s_any = anyv;
        }
      }
      __syncthreads();
      const int cnt = s_cnt;            // multiple of 16
      const int anyPrev = (t > 0) ? s_any : 0;
      const int wPrev = win[b];
      int localmin = 0x7fffffff;

      if (tid < 200) {
        const int n0 = tid * 2;
        const size_t sidx = (size_t)b * NP + n0;
        // hoist sppo post-trace loads ahead of the gather (independent)
        float* sprow = sppo + (size_t)b * 2 * NP + 2 * n0;
        float2 spA = ld_coh2(sprow);
        float2 spB = ld_coh2(sprow + 2);
        float2 sv = *(float2*)(syn + sidx);
        if (anyPrev) {
          if (n0     != wPrev) sv.x -= 0.1f;
          if (n0 + 1 != wPrev) sv.y -= 0.1f;
        }
        float c0 = 0.f, c1 = 0.f;
        for (int j = 0; j < cnt; j += 16) {  // 16 coherent loads in flight
          float2 wv[16];
          #pragma unroll
          for (int u = 0; u < 16; ++u)
            wv[u] = ld_coh2(Wt + (size_t)s_list[j + u] * NP + n0);
          #pragma unroll
          for (int u = 0; u < 16; ++u) { c0 += wv[u].x; c1 += wv[u].y; }
        }
        float2 mv = *(float2*)(mem + sidx);
        float syn0 = fmaf(0.9f, sv.x, c0);
        float syn1 = fmaf(0.9f, sv.y, c1);
        float r0 = (mv.x > 1.0f) ? 1.0f : 0.0f;
        float r1 = (mv.y > 1.0f) ? 1.0f : 0.0f;
        float m0 = fmaf(0.8f, mv.x, syn0) - r0;
        float m1 = fmaf(0.8f, mv.y, syn1) - r1;
        float s0 = (m0 > 1.0f) ? 1.0f : 0.0f;
        float s1 = (m1 > 1.0f) ? 1.0f : 0.0f;
        *(float2*)(syn + sidx) = make_float2(syn0, syn1);
        *(float2*)(mem + sidx) = make_float2(m0, m1);
        float p0 = fmaf(0.9f, spA.y, s0);
        float p1 = fmaf(0.9f, spB.y, s1);
        st_coh2(sprow,     make_float2(s0, p0));
        st_coh2(sprow + 2, make_float2(s1, p1));
        const size_t ridx = (size_t)t * BATCH * NOUT + (size_t)b * NOUT + n0;
        *(float2*)(mem_rec + ridx) = make_float2(m0, m1);
        *(float2*)(spk_rec + ridx) = make_float2(s0, s1);
        if      (s0 != 0.f) localmin = n0;
        else if (s1 != 0.f) localmin = n0 + 1;
      }
      // ballot winner reduction (lanes map to ascending neuron index)
      unsigned long long mm = __ballot(localmin != 0x7fffffff);
      int wmin = 0x7fffffff;
      if (mm) {
        int src = __ffsll(mm) - 1;
        wmin = __shfl(localmin, src);
      }
      if ((tid & 63) == 0) s_red[tid >> 6] = wmin;
      __syncthreads();
      if (tid == 0) {
        int w4 = min(min(s_red[0], s_red[1]), min(s_red[2], s_red[3]));
        win[b] = (w4 == 0x7fffffff) ? 0 : w4;
        st_cohu(anyspk + (t & 1) * 256 + b,
                (w4 != 0x7fffffff) ? 1u : 0u);
      }
    }
    ++bt; gbar(barf, bt, blk);

    // ================= phase 2: STDP weight update =================
    // tr/img already resident in LDS (prefetched last step); stage sppo only.
    if (blk < 169) {
      const int ib = ib0 + (tid >> 4) * 4;
      const int nb = nb0 + (tid & 15) * 2;
      const bool active = (ib < INQ) && (nb < NOUT);
      const int loff = (tid >> 4) * 4;
      const int soff = (tid & 15) * 4;

      float a00=0,a01=0,a10=0,a11=0,a20=0,a21=0,a30=0,a31=0;

      #define SPSTG(c, buf) {                                                  \
        int b0_ = (c) * 32;                                                    \
        for (int q = 0; q < 2; ++q) {                                          \
          int br = b0_ + q * 16 + p2w * 4 + (p2l >> 4);                        \
          gl_lds16c(sppo + (size_t)br * 1024 + scol,                           \
                    &stg_sp[buf][(q * 16 + p2w * 4) * 64]);                    \
        }                                                                      \
      }

      SPSTG(0, 0);
      for (int c = 0; c < 8; ++c) {
        const int buf = c & 1;
        if (c < 7) {
          SPSTG(c + 1, buf ^ 1);
          __builtin_amdgcn_s_waitcnt(0x0F72);     // vmcnt(2): chunk c landed
        } else {
          __builtin_amdgcn_s_waitcnt(0x0F70);     // vmcnt(0)
        }
        __builtin_amdgcn_s_barrier();
        if (active) {
          const float* Ltr = &stg_tr[c * 2048 + loff];
          const float* Lim = &stg_im[c * 2048 + loff];
          const float* Lsp = &stg_sp[buf][soff];
          #pragma unroll 4
          for (int bb = 0; bb < 32; ++bb) {       // b ascending: exact order
            float4 t4 = *(const float4*)(Ltr + bb * 64);
            float4 g4 = *(const float4*)(Lim + bb * 64);
            float4 sp = *(const float4*)(Lsp + bb * 64);
            float ap0 = 1e-3f * sp.x, am0 = 1e-3f * sp.y;
            float ap1 = 1e-3f * sp.z, am1 = 1e-3f * sp.w;
            a00 = fmaf(t4.x, ap0, fmaf(g4.x, -am0, a00));
            a01 = fmaf(t4.x, ap1, fmaf(g4.x, -am1, a01));
            a10 = fmaf(t4.y, ap0, fmaf(g4.y, -am0, a10));
            a11 = fmaf(t4.y, ap1, fmaf(g4.y, -am1, a11));
            a20 = fmaf(t4.z, ap0, fmaf(g4.z, -am0, a20));
            a21 = fmaf(t4.z, ap1, fmaf(g4.z, -am1, a21));
            a30 = fmaf(t4.w, ap0, fmaf(g4.w, -am0, a30));
            a31 = fmaf(t4.w, ap1, fmaf(g4.w, -am1, a31));
          }
        }
        __builtin_amdgcn_s_waitcnt(0xC07F);       // lgkmcnt(0) only
        __builtin_amdgcn_s_barrier();
      }
      #undef SPSTG

      // Wt RMW loads first (oldest in vm queue), then next-step prefetch
      // streams in the epilogue + barrier-drain shadow.
      float2 wl0, wl1, wl2, wl3;
      if (active) {
        wl0 = ld_coh2(Wt + (size_t)(ib + 0) * NP + nb);
        wl1 = ld_coh2(Wt + (size_t)(ib + 1) * NP + nb);
        wl2 = ld_coh2(Wt + (size_t)(ib + 2) * NP + nb);
        wl3 = ld_coh2(Wt + (size_t)(ib + 3) * NP + nb);
      }
      if (t + 1 < T_STEPS) {
        // tr for step t+1 is trN (written this step, drained at last gbar);
        // safe to overwrite stg_tr/stg_im: all waves passed the final
        // lgkmcnt(0)+barrier of the chunk loop above.
        const float* imn = img + (size_t)(t + 1) * BATCH * INQ;
        #pragma unroll
        for (int q = 0; q < 16; ++q) {
          int br = q * 16 + p2w * 4 + (p2l >> 4);
          gl_lds16c(trN + (size_t)br * INQ + icol,
                    &stg_tr[(q * 16 + p2w * 4) * 64]);
          gl_lds16 (imn + (size_t)br * INQ + icol,
                    &stg_im[(q * 16 + p2w * 4) * 64]);
        }
      }
      if (active) {
        float2 wv;
        wv = wl0;
        wv.x = fminf(fmaxf(wv.x + a00, 0.f), 1.f);
        wv.y = fminf(fmaxf(wv.y + a01, 0.f), 1.f);
        st_coh2(Wt + (size_t)(ib + 0) * NP + nb, wv);
        wv = wl1;
        wv.x = fminf(fmaxf(wv.x + a10, 0.f), 1.f);
        wv.y = fminf(fmaxf(wv.y + a11, 0.f), 1.f);
        st_coh2(Wt + (size_t)(ib + 1) * NP + nb, wv);
        wv = wl2;
        wv.x = fminf(fmaxf(wv.x + a20, 0.f), 1.f);
        wv.y = fminf(fmaxf(wv.y + a21, 0.f), 1.f);
        st_coh2(Wt + (size_t)(ib + 2) * NP + nb, wv);
        wv = wl3;
        wv.x = fminf(fmaxf(wv.x + a30, 0.f), 1.f);
        wv.y = fminf(fmaxf(wv.y + a31, 0.f), 1.f);
        st_coh2(Wt + (size_t)(ib + 3) * NP + nb, wv);
      }
    }
    ++bt; gbar(barf, bt, blk);
  }

  // ---- final: W_out[n][i] = Wt[i][n] ----
  for (int e = blk * NTHR + tid; e < NOUT * INQ; e += GRID * NTHR) {
    int n = e / INQ, i = e % INQ;
    Wout[e] = ld_coh(Wt + (size_t)i * NP + n);
  }
}

extern "C" void kernel_launch(void* const* d_in, const int* in_sizes, int n_in,
                              void* d_out, int out_size, void* d_ws, size_t ws_size,
                              hipStream_t stream) {
  const float* img = (const float*)d_in[0];
  const float* W   = (const float*)d_in[1];
  float* out = (float*)d_out;
  float* ws  = (float*)d_ws;

  hipMemsetAsync(d_ws, 0, (size_t)WS_FLOATS * sizeof(float), stream);

  void* args[] = { (void*)&img, (void*)&W, (void*)&out, (void*)&ws };
  hipLaunchCooperativeKernel((const void*)snn_kernel, dim3(GRID), dim3(NTHR),
                             args, 0, stream);
}